// Round 2
// baseline (226.639 us; speedup 1.0000x reference)
//
#include <hip/hip_runtime.h>
#include <math.h>

#define HEADS 8
#define DIM   64
#define DK    24
#define DHK   3
#define BB    4
#define HH    128
#define WW    128
#define NN    (HH*WW)
#define QSCALE 0.125f

// ---------------------------------------------------------------------------
// K1 v3: fused global reduce + attention (last-block-done pattern).
// grid 256 (4 batches x 64 chunks of 256 tokens) x 512 thr (8 waves).
// Each block: LDS-reduce its 256-token partial of Sp[i,c] = sum_n imap[n,i]*x[n,c],
// plain-store to Sp_part[blk][1536], __threadfence (device release), counter
// atomic (1 per block -- replaces R1's 1.57M same-address atomics that
// ping-ponged across XCD L2s). Last block per batch acquires, sums 64
// partials (393KB, ~3us on one CU) and computes the whole attention ->
// Pt[b,24,64]. No K2 launch, no data atomics.
// ---------------------------------------------------------------------------
__global__ __launch_bounds__(512) void reduce_attn(
    const float* __restrict__ imap,    // [B*N,24]
    const float* __restrict__ x,       // [B*N,64]
    const float* __restrict__ Wk,      // [24,24]
    const float* __restrict__ Wq,      // [64,512]
    const float* __restrict__ Wv,      // [64,512]
    const float* __restrict__ rescale, // [8]
    const float* __restrict__ Wp,      // [24,24]
    float* __restrict__ Sp_part,       // [256,1536]
    float* __restrict__ Pt,            // [4,1536]
    int* __restrict__ cnt)             // [4], pre-zeroed
{
    __shared__ float buf[8 * 1540];    // wave partials (pad 1540: stride%32=4)
    __shared__ int isLast;

    const int tid = threadIdx.x;
    const int blk = blockIdx.x;
    const int b = blk >> 6, chunk = blk & 63;
    const int w = tid >> 6, lane = tid & 63;
    const int cq = lane & 15;          // c = cq*4
    const int ig = lane >> 4;          // i = ig*6 .. +5

    // ---- per-block partial reduce over 256 tokens ----
    {
        const long tok0 = (long)b * NN + chunk * 256 + w * 32;
        const float* xp = x    + tok0 * 64 + cq * 4;
        const float* mp = imap + tok0 * 24 + ig * 6;

        float acc[6][4];
        #pragma unroll
        for (int r = 0; r < 6; ++r)
            #pragma unroll
            for (int q = 0; q < 4; ++q) acc[r][q] = 0.f;

        #pragma unroll 4
        for (int t = 0; t < 32; ++t) {
            float4 xv = *(const float4*)(xp + t * 64);
            float2 m0 = *(const float2*)(mp + t * 24);
            float2 m1 = *(const float2*)(mp + t * 24 + 2);
            float2 m2 = *(const float2*)(mp + t * 24 + 4);
            float mm[6] = {m0.x, m0.y, m1.x, m1.y, m2.x, m2.y};
            #pragma unroll
            for (int r = 0; r < 6; ++r) {
                acc[r][0] += mm[r] * xv.x;
                acc[r][1] += mm[r] * xv.y;
                acc[r][2] += mm[r] * xv.z;
                acc[r][3] += mm[r] * xv.w;
            }
        }

        float* pp = buf + w * 1540;
        #pragma unroll
        for (int r = 0; r < 6; ++r) {
            float4 v = {acc[r][0], acc[r][1], acc[r][2], acc[r][3]};
            *(float4*)(pp + (ig * 6 + r) * 64 + cq * 4) = v;
        }
    }
    __syncthreads();

    for (int e = tid; e < 1536; e += 512) {
        float s = 0.f;
        #pragma unroll
        for (int ww = 0; ww < 8; ++ww) s += buf[ww * 1540 + e];
        Sp_part[(long)blk * 1536 + e] = s;
    }

    // ---- publish + count ----
    __threadfence();                   // device-scope release of our stores
    __syncthreads();                   // all threads' stores fenced before atomic
    if (tid == 0) {
        int old = atomicAdd(&cnt[b], 1);
        isLast = (old == 63);
    }
    __syncthreads();
    if (!isLast) return;
    __threadfence();                   // device-scope acquire before reading peers

    // ---- attention for batch b (this block only) ----
    float* Sp_l = buf;                 // [1536]
    float* S_l  = buf + 1536;          // [1536]
    float* att  = buf + 3072;          // [1536]
    float* M_l  = buf + 4608;          // [1536]

    for (int e = tid; e < 1536; e += 512) {
        float s = 0.f;
        const float* p = Sp_part + (long)(b * 64) * 1536 + e;
        #pragma unroll 8
        for (int pb = 0; pb < 64; ++pb) s += p[(long)pb * 1536];
        Sp_l[e] = s;
    }
    __syncthreads();

    // S[ch,c] = sum_i Wk[i,ch] * Sp[i,c]
    for (int e = tid; e < 1536; e += 512) {
        int c = e & 63, ch = e >> 6;
        float s = 0.f;
        #pragma unroll
        for (int i = 0; i < 24; ++i) s += Wk[i * 24 + ch] * Sp_l[i * 64 + c];
        S_l[e] = s;
    }
    __syncthreads();

    // att[ch,d] = QSCALE*rescale[h] * sum_c S[ch,c]*Wq[c, h*64+d]
    for (int e = tid; e < 1536; e += 512) {
        int d = e & 63, ch = e >> 6, h = ch / 3;
        const float* wq = Wq + h * 64 + d;
        const float* sr = S_l + ch * 64;
        float s = 0.f;
        for (int c2 = 0; c2 < 64; ++c2) s += sr[c2] * wq[c2 * 512];
        att[e] = s * QSCALE * rescale[h];
    }
    __syncthreads();

    // softmax over d: 8 waves x 3 rows, wave-parallel shfl
    {
        #pragma unroll
        for (int k = 0; k < 3; ++k) {
            int r = w * 3 + k;
            float a = att[r * 64 + lane];
            float mx = a;
            #pragma unroll
            for (int off = 32; off >= 1; off >>= 1)
                mx = fmaxf(mx, __shfl_xor(mx, off, 64));
            float e = expf(a - mx);
            float sum = e;
            #pragma unroll
            for (int off = 32; off >= 1; off >>= 1)
                sum += __shfl_xor(sum, off, 64);
            att[r * 64 + lane] = e / sum;
        }
    }
    __syncthreads();

    // M[ch,c] = sum_d P[ch,d] * Wv[c, h*64+d]  (Wv row contiguous -> dwordx4)
    for (int e = tid; e < 1536; e += 512) {
        int c = e & 63, ch = e >> 6, h = ch / 3;
        const float* pr = att + ch * 64;
        const float* wv = Wv + c * 512 + h * 64;
        float s = 0.f;
        #pragma unroll
        for (int d = 0; d < 64; ++d) s += pr[d] * wv[d];
        M_l[e] = s;
    }
    __syncthreads();

    // Pt[o,c] = sum_{k,h} M[(h*3+k),c] * Wp[(k*8+h),o]
    for (int e = tid; e < 1536; e += 512) {
        int c = e & 63, o = e >> 6;
        float s = 0.f;
        #pragma unroll
        for (int k = 0; k < 3; ++k)
            #pragma unroll
            for (int h = 0; h < 8; ++h)
                s += M_l[(h * 3 + k) * 64 + c] * Wp[(k * 8 + h) * 24 + o];
        Pt[b * 1536 + e] = s;
    }
}

// ---------------------------------------------------------------------------
// K3 v2: same fused conv structure, 384 threads (6 waves) per 8x8 tile.
// R1 counters: VALUBusy 28%, Occupancy 14% (6 waves/CU), HBM 5% -> pure
// latency bound. 384 thr -> ~18 waves/CU resident (VGPR-limited 3 blocks).
// Work split: ph1 halo pixel x channel-half; ph2 row x chan x col-half
// (slot indices relative to col base -> compile-time); ph3 rows split 2x.
// ---------------------------------------------------------------------------
__global__ __launch_bounds__(384) void conv_fused(
    const float* __restrict__ imap, const float* __restrict__ Wk,
    const float* __restrict__ c1w,  const float* __restrict__ fea,
    const float* __restrict__ c2w,  const float* __restrict__ Pt,
    const float* __restrict__ bp,   float* __restrict__ outp)
{
    __shared__ __align__(16) float kbuf[144 * 28];  // 12x12 halo, stride 28
    __shared__ __align__(16) float y1l[100 * 28];   // 10x10, stride 28

    const int tid = threadIdx.x;
    const int blk = blockIdx.x;
    const int b = blk >> 8, ti = (blk >> 4) & 15, tj = blk & 15;
    const int i0 = ti * 8, j0 = tj * 8;
    const int o = tid % 24;            // out-channel
    const int g = o >> 3;
    const int jj2 = tid / 24;          // 0..15

    // ---- phase 1: kproj on 12x12 halo. 288 threads: (pixel, channel-half) ----
    if (tid < 288) {
        const int px = tid >> 1, half = tid & 1;
        const int pi = px / 12, pj = px % 12;
        const int gi = i0 + pi - 2, gj = j0 + pj - 2;
        float kv[12];
        #pragma unroll
        for (int j = 0; j < 12; ++j) kv[j] = 0.f;
        if (gi >= 0 && gi < HH && gj >= 0 && gj < WW) {
            const float4* m4 = (const float4*)(imap + (((long)b * HH + gi) * WW + gj) * 24);
            float m[24];
            #pragma unroll
            for (int i = 0; i < 6; ++i) {
                float4 v = m4[i];
                m[4*i+0]=v.x; m[4*i+1]=v.y; m[4*i+2]=v.z; m[4*i+3]=v.w;
            }
            for (int i = 0; i < 24; ++i) {
                float mi = m[i];
                #pragma unroll
                for (int j = 0; j < 12; ++j) kv[j] += mi * Wk[i * 24 + half * 12 + j];
            }
        }
        #pragma unroll
        for (int j = 0; j < 12; ++j) kbuf[px * 28 + half * 12 + j] = kv[j];
    }
    __syncthreads();

    // ---- phase 2: y1 = gelu(conv1). 480 tasks (10 rows x 2 col-halves x 24 o) ----
    {
        float wr[8][9];   // conv1 weights for channel o, OIHW-linear
        {
            const float4* wp = (const float4*)(c1w + o * 72);
            #pragma unroll
            for (int t = 0; t < 18; ++t) ((float4*)wr)[t] = wp[t];
        }
        for (int task = tid; task < 480; task += 384) {
            const int r = task / 48;
            const int half = (task / 24) & 1;
            const int c0 = half * 5;           // output cols c0..c0+4
            float wc[3][3][8];                 // [slot][di][ic], slot relative to c0
            #pragma unroll
            for (int slot = 0; slot < 2; ++slot)
                #pragma unroll
                for (int di = 0; di < 3; ++di) {
                    const float* p = kbuf + ((r + di) * 12 + c0 + slot) * 28 + g * 8;
                    *(float4*)&wc[slot][di][0] = *(const float4*)(p);
                    *(float4*)&wc[slot][di][4] = *(const float4*)(p + 4);
                }
            #pragma unroll
            for (int c5 = 0; c5 < 5; ++c5) {
                const int s2 = (c5 + 2) % 3;
                #pragma unroll
                for (int di = 0; di < 3; ++di) {
                    const float* p = kbuf + ((r + di) * 12 + c0 + c5 + 2) * 28 + g * 8;
                    *(float4*)&wc[s2][di][0] = *(const float4*)(p);
                    *(float4*)&wc[s2][di][4] = *(const float4*)(p + 4);
                }
                float s = 0.f;
                #pragma unroll
                for (int dj = 0; dj < 3; ++dj) {
                    const int sl = (c5 + dj) % 3;
                    #pragma unroll
                    for (int di = 0; di < 3; ++di)
                        #pragma unroll
                        for (int ic = 0; ic < 8; ++ic)
                            s += wc[sl][di][ic] * wr[ic][di * 3 + dj];
                }
                const int gi = i0 + r - 1, gj = j0 + c0 + c5 - 1;
                float val = 0.f;
                if (gi >= 0 && gi < HH && gj >= 0 && gj < WW)
                    val = 0.5f * s * (1.f + erff(s * 0.70710678f));
                y1l[(r * 10 + c0 + c5) * 28 + o] = val;
            }
        }
    }
    __syncthreads();

    // ---- phase 3: out = fea@P + bp + conv2(y1l). (o, col jj, 4-row group rh) ----
    const int jj = jj2 & 7, rh = jj2 >> 3;     // rows rh*4 .. rh*4+3
    float wr[8][9];
    {
        const float4* wp = (const float4*)(c2w + o * 72);
        #pragma unroll
        for (int t = 0; t < 18; ++t) ((float4*)wr)[t] = wp[t];
    }

    float acc[4];
    {
        const float bo = bp[o];
        #pragma unroll
        for (int lr = 0; lr < 4; ++lr) acc[lr] = bo;
        const float* PtRow = Pt + b * 1536 + o * 64;
        const float* feaB = fea + (((long)(b * HH + i0 + rh * 4)) * WW + (j0 + jj)) * 64;
        for (int cq = 0; cq < 16; ++cq) {
            float4 p = *(const float4*)(PtRow + cq * 4);
            #pragma unroll
            for (int lr = 0; lr < 4; ++lr) {
                float4 f = *(const float4*)(feaB + (long)lr * WW * 64 + cq * 4);
                acc[lr] += f.x * p.x + f.y * p.y + f.z * p.z + f.w * p.w;
            }
        }
    }

    float win[3][3][8];   // [row slot][dj][ic]
    #define LROW(R, SLOT)                                                     \
    {                                                                         \
        const float* rp_ = y1l + ((R) * 10 + jj) * 28 + g * 8;                \
        *(float4*)&win[SLOT][0][0] = *(const float4*)(rp_);                   \
        *(float4*)&win[SLOT][0][4] = *(const float4*)(rp_ + 4);               \
        *(float4*)&win[SLOT][1][0] = *(const float4*)(rp_ + 28);              \
        *(float4*)&win[SLOT][1][4] = *(const float4*)(rp_ + 32);              \
        *(float4*)&win[SLOT][2][0] = *(const float4*)(rp_ + 56);              \
        *(float4*)&win[SLOT][2][4] = *(const float4*)(rp_ + 60);              \
    }

    LROW(rh * 4 + 0, 0)
    LROW(rh * 4 + 1, 1)
    #pragma unroll
    for (int lr = 0; lr < 4; ++lr) {
        LROW(rh * 4 + lr + 2, (lr + 2) % 3)
        float s = 0.f;
        #pragma unroll
        for (int di = 0; di < 3; ++di) {
            const int slot = (lr + di) % 3;
            #pragma unroll
            for (int dj = 0; dj < 3; ++dj)
                #pragma unroll
                for (int ic = 0; ic < 8; ++ic)
                    s += win[slot][dj][ic] * wr[ic][di * 3 + dj];
        }
        outp[((long)((b * HH + i0 + rh * 4 + lr) * WW + j0 + jj)) * 24 + o] = acc[lr] + s;
    }
    #undef LROW
}

// ---------------------------------------------------------------------------
extern "C" void kernel_launch(void* const* d_in, const int* in_sizes, int n_in,
                              void* d_out, int out_size, void* d_ws, size_t ws_size,
                              hipStream_t stream) {
    const float* x_in    = (const float*)d_in[0];
    const float* fea     = (const float*)d_in[1];
    const float* imap    = (const float*)d_in[2];
    const float* Wq      = (const float*)d_in[3];
    const float* Wk      = (const float*)d_in[4];
    const float* Wv      = (const float*)d_in[5];
    const float* rescale = (const float*)d_in[6];
    const float* Wp      = (const float*)d_in[7];
    const float* bp      = (const float*)d_in[8];
    const float* c1w     = (const float*)d_in[9];
    const float* c2w     = (const float*)d_in[10];
    float* out = (float*)d_out;

    float* ws      = (float*)d_ws;
    float* Sp_part = ws;                    // 256*1536 = 393,216 floats
    float* Pt      = ws + 393216;           // 6,144 floats
    int*   cnt     = (int*)(ws + 399360);   // 4 ints

    hipMemsetAsync(cnt, 0, 4 * sizeof(int), stream);
    reduce_attn<<<256, 512, 0, stream>>>(imap, x_in, Wk, Wq, Wv, rescale, Wp,
                                         Sp_part, Pt, cnt);
    conv_fused<<<BB * 256, 384, 0, stream>>>(imap, Wk, c1w, fea, c2w, Pt, bp, out);
}

// Round 4
// 157.709 us; speedup vs baseline: 1.4371x; 1.4371x over previous
//
#include <hip/hip_runtime.h>
#include <math.h>

#define HEADS 8
#define DIM   64
#define DK    24
#define DHK   3
#define BB    4
#define HH    128
#define WW    128
#define NN    (HH*WW)
#define QSCALE 0.125f

// ---------------------------------------------------------------------------
// K1 v4: token-partial reduce, NO data atomics (R1's 1.57M same-address
// atomics ping-ponged across XCDs; R3's coop fusion failed correctness --
// kernel boundaries are the proven cross-XCD coherence mechanism).
// grid 256 (4b x 64 chunks of 256 tokens) x 1024 thr = 16 waves/CU (50% occ
// vs R0's 12%). Each wave handles 16 tokens; 16-way LDS merge; plain stores
// to Sp_part[256][1536] (proven ws footprint). Blocks 0-3 zero Pt for K2.
// ---------------------------------------------------------------------------
__global__ __launch_bounds__(1024) void s_reduce(
    const float* __restrict__ imap,   // [B*N,24]
    const float* __restrict__ x,      // [B*N,64]
    float* __restrict__ Sp_part,      // [256,1536]
    float* __restrict__ Pt)           // [4,1536] -> zeroed here
{
    __shared__ float part[16 * 1540];   // 98.5 KB, stride 1540 (pad: %32==4)
    const int tid = threadIdx.x;
    const int blk = blockIdx.x;
    const int b = blk >> 6, chunk = blk & 63;
    const int w = tid >> 6, lane = tid & 63;
    const int cq = lane & 15;         // c = cq*4
    const int ig = lane >> 4;         // i = ig*6 .. +5

    const long tok0 = (long)b * NN + chunk * 256 + w * 16;
    const float* xp = x    + tok0 * 64 + cq * 4;
    const float* mp = imap + tok0 * 24 + ig * 6;

    float acc[6][4];
    #pragma unroll
    for (int r = 0; r < 6; ++r)
        #pragma unroll
        for (int q = 0; q < 4; ++q) acc[r][q] = 0.f;

    #pragma unroll 4
    for (int t = 0; t < 16; ++t) {
        float4 xv = *(const float4*)(xp + t * 64);
        float2 m0 = *(const float2*)(mp + t * 24);
        float2 m1 = *(const float2*)(mp + t * 24 + 2);
        float2 m2 = *(const float2*)(mp + t * 24 + 4);
        float mm[6] = {m0.x, m0.y, m1.x, m1.y, m2.x, m2.y};
        #pragma unroll
        for (int r = 0; r < 6; ++r) {
            acc[r][0] += mm[r] * xv.x;
            acc[r][1] += mm[r] * xv.y;
            acc[r][2] += mm[r] * xv.z;
            acc[r][3] += mm[r] * xv.w;
        }
    }

    float* pp = part + w * 1540;
    #pragma unroll
    for (int r = 0; r < 6; ++r) {
        float4 v = {acc[r][0], acc[r][1], acc[r][2], acc[r][3]};
        *(float4*)(pp + (ig * 6 + r) * 64 + cq * 4) = v;
    }
    __syncthreads();

    for (int e = tid; e < 1536; e += 1024) {
        float s = 0.f;
        #pragma unroll
        for (int ww = 0; ww < 16; ++ww) s += part[ww * 1540 + e];
        Sp_part[(long)blk * 1536 + e] = s;
    }
    if (blk < 4)
        for (int e = tid; e < 1536; e += 1024) Pt[blk * 1536 + e] = 0.f;
}

// ---------------------------------------------------------------------------
// K2 v4: per-(b,h) slab reduce + attention (R1-proven math). grid 32 x 256.
// Reduce: 64 slabs x 6 elems/thread, unroll-8 for memory-level parallelism
// (393KB/block from L2/L3). Then S -> att -> softmax(wave-parallel) -> M ->
// Pt via atomicAdd (only 49K adds, 8-way h contention -- negligible).
// ---------------------------------------------------------------------------
__global__ __launch_bounds__(256) void attn_fused(
    const float* __restrict__ Sp_part, // [256,1536]
    const float* __restrict__ Wk,      // [24,24]
    const float* __restrict__ Wq,      // [64,512]
    const float* __restrict__ Wv,      // [64,512]
    const float* __restrict__ rescale, // [8]
    const float* __restrict__ Wp,      // [24,24]
    float* __restrict__ Pt)            // [4,1536] pre-zeroed by K1
{
    __shared__ float Sp_l[1536];
    __shared__ float sS[192];        // S rows (reused for M)
    __shared__ float sP[192];        // softmax'd rows
    __shared__ float Wv_l[64 * 65];  // Wv[:, h*64..+63], stride 65

    const int tid = threadIdx.x, blk = blockIdx.x;
    const int b = blk >> 3, h = blk & 7;
    const int w = tid >> 6, lane = tid & 63;

    // ---- reduce 64 partial slabs for batch b ----
    {
        float s[6] = {0.f, 0.f, 0.f, 0.f, 0.f, 0.f};
        const float* p = Sp_part + (long)(b * 64) * 1536 + tid;
        #pragma unroll 8
        for (int pb = 0; pb < 64; ++pb)
            #pragma unroll
            for (int k = 0; k < 6; ++k)
                s[k] += p[(long)pb * 1536 + k * 256];
        #pragma unroll
        for (int k = 0; k < 6; ++k) Sp_l[tid + k * 256] = s[k];
    }
    for (int e = tid; e < 4096; e += 256) {
        int c = e >> 6, d = e & 63;
        Wv_l[c * 65 + d] = Wv[c * 512 + h * 64 + d];
    }
    __syncthreads();

    // S[ch,c] = sum_i Wk[i,ch]*Sp[i,c]   (waves 0..2, ch = h*3+w, c = lane)
    if (w < 3) {
        const float* wk = Wk + (h * 3 + w);
        float s = 0.f;
        #pragma unroll
        for (int i = 0; i < 24; ++i) s += wk[i * 24] * Sp_l[i * 64 + lane];
        sS[w * 64 + lane] = s;
    }
    __syncthreads();

    // att row (d = lane) + wave-parallel softmax
    if (w < 3) {
        const float* wq = Wq + h * 64 + lane;
        const float* sr = sS + w * 64;
        float a = 0.f;
        #pragma unroll 8
        for (int c = 0; c < 64; ++c) a += sr[c] * wq[c * 512];
        a *= QSCALE * rescale[h];
        float mx = a;
        #pragma unroll
        for (int off = 32; off >= 1; off >>= 1)
            mx = fmaxf(mx, __shfl_xor(mx, off, 64));
        float e = expf(a - mx);
        float sum = e;
        #pragma unroll
        for (int off = 32; off >= 1; off >>= 1)
            sum += __shfl_xor(sum, off, 64);
        sP[w * 64 + lane] = e / sum;
    }
    __syncthreads();

    // M[ch,c] = sum_d P[ch,d]*Wv[c,h*64+d]; reuse sS
    if (w < 3) {
        const float* pr = sP + w * 64;
        const float* wv = Wv_l + lane * 65;
        float m = 0.f;
        #pragma unroll
        for (int d = 0; d < 64; ++d) m += pr[d] * wv[d];
        sS[w * 64 + lane] = m;
    }
    __syncthreads();

    // Pt[b,o,c] += sum_k M[k,c]*Wp[(k*8+h),o]
    for (int q = tid; q < 1536; q += 256) {
        int o = q >> 6, c = q & 63;
        float v = 0.f;
        #pragma unroll
        for (int k = 0; k < 3; ++k)
            v += sS[k * 64 + c] * Wp[(k * 8 + h) * 24 + o];
        atomicAdd(&Pt[b * 1536 + o * 64 + c], v);
    }
}

// ---------------------------------------------------------------------------
// K3: conv_fused v1 body, verbatim (proven 48us across R0/R1).
// ---------------------------------------------------------------------------
__global__ __launch_bounds__(192, 2) void conv_fused(
    const float* __restrict__ imap, const float* __restrict__ Wk,
    const float* __restrict__ c1w,  const float* __restrict__ fea,
    const float* __restrict__ c2w,  const float* __restrict__ Pt,
    const float* __restrict__ bp,   float* __restrict__ outp)
{
    __shared__ __align__(16) float kbuf[144 * 28];  // 12x12 halo, stride 28
    __shared__ __align__(16) float y1l[100 * 28];   // 10x10, stride 28

    const int tid = threadIdx.x;
    const int blk = blockIdx.x;
    const int b = blk >> 8, ti = (blk >> 4) & 15, tj = blk & 15;
    const int i0 = ti * 8, j0 = tj * 8;
    const int o = tid % 24, jj = tid / 24;   // o: out-channel; jj: 0..7
    const int g = o >> 3;

    // ---- phase 1: kproj on the 12x12 halo (threads 0..143) ----
    if (tid < 144) {
        const int pi = tid / 12, pj = tid % 12;
        const int gi = i0 + pi - 2, gj = j0 + pj - 2;
        float kv[24];
        #pragma unroll
        for (int j = 0; j < 24; ++j) kv[j] = 0.f;
        if (gi >= 0 && gi < HH && gj >= 0 && gj < WW) {
            const float4* m4 = (const float4*)(imap + (((long)b * HH + gi) * WW + gj) * 24);
            float m[24];
            #pragma unroll
            for (int i = 0; i < 6; ++i) {
                float4 v = m4[i];
                m[4*i+0]=v.x; m[4*i+1]=v.y; m[4*i+2]=v.z; m[4*i+3]=v.w;
            }
            for (int i = 0; i < 24; ++i) {
                float mi = m[i];
                #pragma unroll
                for (int j = 0; j < 24; ++j) kv[j] += mi * Wk[i * 24 + j];
            }
        }
        #pragma unroll
        for (int j = 0; j < 24; ++j) kbuf[tid * 28 + j] = kv[j];
    }
    __syncthreads();

    // ---- phase 2: y1 = gelu(conv1) on 10x10 -> y1l ----
    {
        float wr[8][9];   // wr[ic][di*3+dj], OIHW-linear
        {
            const float4* wp = (const float4*)(c1w + o * 72);
            #pragma unroll
            for (int t = 0; t < 18; ++t) ((float4*)wr)[t] = wp[t];
        }
        for (int task = tid; task < 240; task += 192) {
            const int r = task / 24;           // y1l row 0..9
            float wc[3][3][8];                 // [col slot][di][ic]
            #pragma unroll
            for (int slot = 0; slot < 2; ++slot)
                #pragma unroll
                for (int di = 0; di < 3; ++di) {
                    const float* p = kbuf + ((r + di) * 12 + slot) * 28 + g * 8;
                    *(float4*)&wc[slot][di][0] = *(const float4*)(p);
                    *(float4*)&wc[slot][di][4] = *(const float4*)(p + 4);
                }
            #pragma unroll
            for (int c = 0; c < 10; ++c) {
                const int s2 = (c + 2) % 3;
                #pragma unroll
                for (int di = 0; di < 3; ++di) {
                    const float* p = kbuf + ((r + di) * 12 + (c + 2)) * 28 + g * 8;
                    *(float4*)&wc[s2][di][0] = *(const float4*)(p);
                    *(float4*)&wc[s2][di][4] = *(const float4*)(p + 4);
                }
                float s = 0.f;
                #pragma unroll
                for (int dj = 0; dj < 3; ++dj) {
                    const int sl = (c + dj) % 3;
                    #pragma unroll
                    for (int di = 0; di < 3; ++di)
                        #pragma unroll
                        for (int ic = 0; ic < 8; ++ic)
                            s += wc[sl][di][ic] * wr[ic][di * 3 + dj];
                }
                const int gi = i0 + r - 1, gj = j0 + c - 1;
                float val = 0.f;
                if (gi >= 0 && gi < HH && gj >= 0 && gj < WW)
                    val = 0.5f * s * (1.f + erff(s * 0.70710678f));
                y1l[(r * 10 + c) * 28 + o] = val;
            }
        }
    }
    __syncthreads();

    // ---- phase 3: out = fea@P + bp + conv2(y1l) on 8x8 ----
    float wr[8][9];
    {
        const float4* wp = (const float4*)(c2w + o * 72);
        #pragma unroll
        for (int t = 0; t < 18; ++t) ((float4*)wr)[t] = wp[t];
    }

    float acc[8];
    {
        const float bo = bp[o];
        #pragma unroll
        for (int ii = 0; ii < 8; ++ii) acc[ii] = bo;
        const float* PtRow = Pt + b * 1536 + o * 64;
        const float* feaB = fea + (((long)(b * HH + i0)) * WW + (j0 + jj)) * 64;
        for (int cq = 0; cq < 16; ++cq) {
            float4 p = *(const float4*)(PtRow + cq * 4);
            #pragma unroll
            for (int ii = 0; ii < 8; ++ii) {
                float4 f = *(const float4*)(feaB + (long)ii * WW * 64 + cq * 4);
                acc[ii] += f.x * p.x + f.y * p.y + f.z * p.z + f.w * p.w;
            }
        }
    }

    float win[3][3][8];   // [row slot][dj][ic]
    #define LROW(R, SLOT)                                                     \
    {                                                                         \
        const float* rp_ = y1l + ((R) * 10 + jj) * 28 + g * 8;                \
        *(float4*)&win[SLOT][0][0] = *(const float4*)(rp_);                   \
        *(float4*)&win[SLOT][0][4] = *(const float4*)(rp_ + 4);               \
        *(float4*)&win[SLOT][1][0] = *(const float4*)(rp_ + 28);              \
        *(float4*)&win[SLOT][1][4] = *(const float4*)(rp_ + 32);              \
        *(float4*)&win[SLOT][2][0] = *(const float4*)(rp_ + 56);              \
        *(float4*)&win[SLOT][2][4] = *(const float4*)(rp_ + 60);              \
    }

    LROW(0, 0)
    LROW(1, 1)
    #pragma unroll
    for (int ii = 0; ii < 8; ++ii) {
        LROW(ii + 2, (ii + 2) % 3)
        float s = 0.f;
        #pragma unroll
        for (int di = 0; di < 3; ++di) {
            const int slot = (ii + di) % 3;
            #pragma unroll
            for (int dj = 0; dj < 3; ++dj)
                #pragma unroll
                for (int ic = 0; ic < 8; ++ic)
                    s += win[slot][dj][ic] * wr[ic][di * 3 + dj];
        }
        outp[((long)((b * HH + i0 + ii) * WW + j0)) * 24 + tid] = acc[ii] + s;
    }
    #undef LROW
}

// ---------------------------------------------------------------------------
extern "C" void kernel_launch(void* const* d_in, const int* in_sizes, int n_in,
                              void* d_out, int out_size, void* d_ws, size_t ws_size,
                              hipStream_t stream) {
    const float* x_in    = (const float*)d_in[0];
    const float* fea     = (const float*)d_in[1];
    const float* imap    = (const float*)d_in[2];
    const float* Wq      = (const float*)d_in[3];
    const float* Wk      = (const float*)d_in[4];
    const float* Wv      = (const float*)d_in[5];
    const float* rescale = (const float*)d_in[6];
    const float* Wp      = (const float*)d_in[7];
    const float* bp      = (const float*)d_in[8];
    const float* c1w     = (const float*)d_in[9];
    const float* c2w     = (const float*)d_in[10];
    float* out = (float*)d_out;

    float* ws      = (float*)d_ws;
    float* Sp_part = ws;                     // 256*1536 = 393,216 floats
    float* Pt      = ws + 393216;            // 6,144 floats

    s_reduce<<<256, 1024, 0, stream>>>(imap, x_in, Sp_part, Pt);
    attn_fused<<<32, 256, 0, stream>>>(Sp_part, Wk, Wq, Wv, rescale, Wp, Pt);
    conv_fused<<<BB * 256, 192, 0, stream>>>(imap, Wk, c1w, fea, c2w, Pt, bp, out);
}